// Round 2
// baseline (1617.091 us; speedup 1.0000x reference)
//
#include <hip/hip_runtime.h>

#define LEAF   16384
#define NNODE  (2*LEAF-1)
#define LATENT 256
#define HIDDEN 512
#define SYM    64
#define BOX    128

// ---------------------------------------------------------------------------
// Leaf kernel: h[r][c] = tanh( sum_k shape[k][r]*Wb[k][c] + bb[c] )
// grid = LEAF/16 blocks, 256 threads (one output column per thread, 16 rows)
// ---------------------------------------------------------------------------
__global__ __launch_bounds__(256) void leaf_kernel(
    const float* __restrict__ shape, const float* __restrict__ Wb,
    const float* __restrict__ bb, float* __restrict__ h)
{
    __shared__ float Xs[16][132];   // 16 rows x 128 K, padded (16B-aligned rows)
    const int r0 = blockIdx.x * 16;
    const int t  = threadIdx.x;

    // load 16x128 tile of boxes = shape^T. tasks: r = task&15 (fast), kg = task>>4
    for (int it = 0; it < 2; ++it) {
        int task = t + it * 256;
        int r  = task & 15;
        int kg = task >> 4;          // 0..31, group of 4 K values
        #pragma unroll
        for (int j = 0; j < 4; ++j)
            Xs[r][4*kg + j] = shape[(size_t)(4*kg + j) * LEAF + r0 + r];
    }
    __syncthreads();

    float acc[16];
    #pragma unroll
    for (int r = 0; r < 16; ++r) acc[r] = 0.f;

    const int c = t;   // 0..255
    for (int k = 0; k < BOX; k += 4) {
        float w0 = Wb[(k+0)*LATENT + c];
        float w1 = Wb[(k+1)*LATENT + c];
        float w2 = Wb[(k+2)*LATENT + c];
        float w3 = Wb[(k+3)*LATENT + c];
        #pragma unroll
        for (int r = 0; r < 16; ++r) {
            float4 x = *reinterpret_cast<const float4*>(&Xs[r][k]);
            acc[r] = fmaf(x.x, w0, acc[r]);
            acc[r] = fmaf(x.y, w1, acc[r]);
            acc[r] = fmaf(x.z, w2, acc[r]);
            acc[r] = fmaf(x.w, w3, acc[r]);
        }
    }
    float bias = bb[c];
    #pragma unroll
    for (int r = 0; r < 16; ++r)
        h[(size_t)(r0 + r) * LATENT + c] = tanhf(acc[r] + bias);
}

// ---------------------------------------------------------------------------
// Level kernel: for nodes i = start..start+n-1 (one tree level):
//   a = h[k0-1], b = h[k1-1], s = param[k0-1]
//   H1 = tanh(tanh(a@Wl + b@Wr + b1) @ W2 + b2)           (all rows)
//   H2 = tanh(tanh(a@Wsl + s@Wsr + bs1) @ Ws2 + bs2)      (rows with k2==1)
//   h[i] = k2 ? H2 : H1
// block = 256 threads, BM = 16 rows per block.
// ---------------------------------------------------------------------------
__global__ __launch_bounds__(256) void level_kernel(
    float* __restrict__ h, const int* __restrict__ kids, const float* __restrict__ param,
    const float* __restrict__ Wl, const float* __restrict__ Wr, const float* __restrict__ b1,
    const float* __restrict__ W2, const float* __restrict__ b2,
    const float* __restrict__ Wsl, const float* __restrict__ Wsr, const float* __restrict__ bs1,
    const float* __restrict__ Ws2, const float* __restrict__ bs2,
    int start, int n)
{
    __shared__ float Xs[16][512];   // [a | b] per row
    __shared__ float Us[16][512];   // stage-1 output, later reused as V
    __shared__ float Ss[16][64];    // sym params of left child
    __shared__ int k0s[16], k1s[16], k2s[16], symlist[16];
    __shared__ int nsym_s;

    const int t  = threadIdx.x;
    const int m0 = blockIdx.x * 16;

    if (t < 16) {
        int m  = m0 + t;
        int mm = (m < n) ? m : (n - 1);    // clamp tail rows (results discarded)
        int i  = start + mm;
        k0s[t] = kids[3*i]     - 1;
        k1s[t] = kids[3*i + 1] - 1;
        k2s[t] = (m < n) ? kids[3*i + 2] : 0;
    }
    __syncthreads();
    if (t == 0) {
        int c = 0;
        for (int r = 0; r < 16; ++r) {
            int m = m0 + r;
            if (m < n && k2s[r]) symlist[c++] = r;
        }
        nsym_s = c;
    }

    // load X rows (coalesced, 2 x 1KB per row) and S rows
    for (int r = 0; r < 16; ++r) {
        Xs[r][t]       = h[(size_t)k0s[r] * LATENT + t];
        Xs[r][t + 256] = h[(size_t)k1s[r] * LATENT + t];
    }
    for (int it = 0; it < 4; ++it) {
        int task = t + it * 256;          // 16*64 tasks
        int r = task >> 6;
        int k = task & 63;
        Ss[r][k] = param[(size_t)k0s[r] * SYM + k];
    }
    __syncthreads();

    // -------- stage 1: U = tanh(X @ [Wl;Wr] + b1), cols (t, t+256) ----------
    float acc1[16], acc2[16];
    #pragma unroll
    for (int r = 0; r < 16; ++r) { acc1[r] = 0.f; acc2[r] = 0.f; }

    for (int k = 0; k < 256; k += 4) {
        float wa[4], wb[4];
        #pragma unroll
        for (int kk = 0; kk < 4; ++kk) {
            wa[kk] = Wl[(k+kk)*HIDDEN + t];
            wb[kk] = Wl[(k+kk)*HIDDEN + t + 256];
        }
        #pragma unroll
        for (int r = 0; r < 16; ++r) {
            float4 x = *reinterpret_cast<const float4*>(&Xs[r][k]);
            acc1[r] = fmaf(x.x,wa[0],fmaf(x.y,wa[1],fmaf(x.z,wa[2],fmaf(x.w,wa[3],acc1[r]))));
            acc2[r] = fmaf(x.x,wb[0],fmaf(x.y,wb[1],fmaf(x.z,wb[2],fmaf(x.w,wb[3],acc2[r]))));
        }
    }
    for (int k = 0; k < 256; k += 4) {
        float wa[4], wb[4];
        #pragma unroll
        for (int kk = 0; kk < 4; ++kk) {
            wa[kk] = Wr[(k+kk)*HIDDEN + t];
            wb[kk] = Wr[(k+kk)*HIDDEN + t + 256];
        }
        #pragma unroll
        for (int r = 0; r < 16; ++r) {
            float4 x = *reinterpret_cast<const float4*>(&Xs[r][256 + k]);
            acc1[r] = fmaf(x.x,wa[0],fmaf(x.y,wa[1],fmaf(x.z,wa[2],fmaf(x.w,wa[3],acc1[r]))));
            acc2[r] = fmaf(x.x,wb[0],fmaf(x.y,wb[1],fmaf(x.z,wb[2],fmaf(x.w,wb[3],acc2[r]))));
        }
    }
    {
        float bA = b1[t], bB = b1[t + 256];
        #pragma unroll
        for (int r = 0; r < 16; ++r) {
            Us[r][t]       = tanhf(acc1[r] + bA);
            Us[r][t + 256] = tanhf(acc2[r] + bB);
        }
    }
    __syncthreads();

    // -------- stage 2: H1 = tanh(U @ W2 + b2), col t; write non-sym rows ----
    float acc[16];
    #pragma unroll
    for (int r = 0; r < 16; ++r) acc[r] = 0.f;
    for (int k = 0; k < 512; k += 4) {
        float w[4];
        #pragma unroll
        for (int kk = 0; kk < 4; ++kk) w[kk] = W2[(k+kk)*LATENT + t];
        #pragma unroll
        for (int r = 0; r < 16; ++r) {
            float4 x = *reinterpret_cast<const float4*>(&Us[r][k]);
            acc[r] = fmaf(x.x,w[0],fmaf(x.y,w[1],fmaf(x.z,w[2],fmaf(x.w,w[3],acc[r]))));
        }
    }
    {
        float bc = b2[t];
        #pragma unroll
        for (int r = 0; r < 16; ++r) {
            int m = m0 + r;
            if (m < n && !k2s[r])
                h[(size_t)(start + m) * LATENT + t] = tanhf(acc[r] + bc);
        }
    }
    __syncthreads();   // Us fully consumed; safe to reuse as V

    // -------- sym path: V = tanh(A@Wsl + S@Wsr + bs1) for k2 rows -----------
    const int nsym = nsym_s;
    for (int base = 0; base < nsym; base += 4) {
        int sr[4];
        #pragma unroll
        for (int j = 0; j < 4; ++j) {
            int idx = base + j;
            sr[j] = symlist[idx < nsym ? idx : nsym - 1];
        }
        float v1[4], v2[4];
        #pragma unroll
        for (int j = 0; j < 4; ++j) { v1[j] = 0.f; v2[j] = 0.f; }
        for (int k = 0; k < 256; k += 4) {
            float wa[4], wb[4];
            #pragma unroll
            for (int kk = 0; kk < 4; ++kk) {
                wa[kk] = Wsl[(k+kk)*HIDDEN + t];
                wb[kk] = Wsl[(k+kk)*HIDDEN + t + 256];
            }
            #pragma unroll
            for (int j = 0; j < 4; ++j) {
                float4 x = *reinterpret_cast<const float4*>(&Xs[sr[j]][k]);  // A = first half
                v1[j] = fmaf(x.x,wa[0],fmaf(x.y,wa[1],fmaf(x.z,wa[2],fmaf(x.w,wa[3],v1[j]))));
                v2[j] = fmaf(x.x,wb[0],fmaf(x.y,wb[1],fmaf(x.z,wb[2],fmaf(x.w,wb[3],v2[j]))));
            }
        }
        for (int k = 0; k < 64; k += 4) {
            float wa[4], wb[4];
            #pragma unroll
            for (int kk = 0; kk < 4; ++kk) {
                wa[kk] = Wsr[(k+kk)*HIDDEN + t];
                wb[kk] = Wsr[(k+kk)*HIDDEN + t + 256];
            }
            #pragma unroll
            for (int j = 0; j < 4; ++j) {
                float4 x = *reinterpret_cast<const float4*>(&Ss[sr[j]][k]);
                v1[j] = fmaf(x.x,wa[0],fmaf(x.y,wa[1],fmaf(x.z,wa[2],fmaf(x.w,wa[3],v1[j]))));
                v2[j] = fmaf(x.x,wb[0],fmaf(x.y,wb[1],fmaf(x.z,wb[2],fmaf(x.w,wb[3],v2[j]))));
            }
        }
        float bA = bs1[t], bB = bs1[t + 256];
        #pragma unroll
        for (int j = 0; j < 4; ++j) {
            Us[base + j][t]       = tanhf(v1[j] + bA);
            Us[base + j][t + 256] = tanhf(v2[j] + bB);
        }
    }
    __syncthreads();

    // -------- H2 = tanh(V @ Ws2 + bs2); overwrite sym rows ------------------
    for (int base = 0; base < nsym; base += 4) {
        float a2[4];
        #pragma unroll
        for (int j = 0; j < 4; ++j) a2[j] = 0.f;
        for (int k = 0; k < 512; k += 4) {
            float w[4];
            #pragma unroll
            for (int kk = 0; kk < 4; ++kk) w[kk] = Ws2[(k+kk)*LATENT + t];
            #pragma unroll
            for (int j = 0; j < 4; ++j) {
                float4 x = *reinterpret_cast<const float4*>(&Us[base + j][k]);
                a2[j] = fmaf(x.x,w[0],fmaf(x.y,w[1],fmaf(x.z,w[2],fmaf(x.w,w[3],a2[j]))));
            }
        }
        float bc = bs2[t];
        #pragma unroll
        for (int j = 0; j < 4; ++j) {
            int idx = base + j;
            if (idx < nsym) {
                int r = symlist[idx];
                int m = m0 + r;
                h[(size_t)(start + m) * LATENT + t] = tanhf(a2[j] + bc);
            }
        }
    }
}

extern "C" void kernel_launch(void* const* d_in, const int* in_sizes, int n_in,
                              void* d_out, int out_size, void* d_ws, size_t ws_size,
                              hipStream_t stream) {
    const int*   kids  = (const int*)  d_in[0];
    const float* shape = (const float*)d_in[1];
    const float* param = (const float*)d_in[2];
    const float* Wb    = (const float*)d_in[3];
    const float* bb    = (const float*)d_in[4];
    const float* Wl    = (const float*)d_in[5];
    const float* Wr    = (const float*)d_in[6];
    const float* b1    = (const float*)d_in[7];
    const float* W2    = (const float*)d_in[8];
    const float* b2    = (const float*)d_in[9];
    const float* Wsl   = (const float*)d_in[10];
    const float* Wsr   = (const float*)d_in[11];
    const float* bs1   = (const float*)d_in[12];
    const float* Ws2   = (const float*)d_in[13];
    const float* bs2   = (const float*)d_in[14];

    float* h   = (float*)d_ws;                    // NNODE x 256 fp32 = 33.6 MB
    float* out = (float*)d_out;

    leaf_kernel<<<LEAF/16, 256, 0, stream>>>(shape, Wb, bb, h);

    int start = LEAF;
    for (int n = LEAF/2; n >= 1; n >>= 1) {
        int grid = (n + 15) / 16;
        level_kernel<<<grid, 256, 0, stream>>>(h, kids, param,
                                               Wl, Wr, b1, W2, b2,
                                               Wsl, Wsr, bs1, Ws2, bs2,
                                               start, n);
        start += n;
    }

    hipMemcpyAsync(out, h + (size_t)(NNODE - 1) * LATENT,
                   LATENT * sizeof(float), hipMemcpyDeviceToDevice, stream);
}

// Round 4
// 804.724 us; speedup vs baseline: 2.0095x; 2.0095x over previous
//
#include <hip/hip_runtime.h>

#define LEAF   16384
#define NNODE  (2*LEAF-1)
#define LATENT 256
#define HIDDEN 512
#define SYM    64
#define BOX    128

using short8 = __attribute__((ext_vector_type(8))) short;
using f32x4  = __attribute__((ext_vector_type(4))) float;

__device__ inline unsigned short f2bf(float x){
    unsigned u = __float_as_uint(x);
    u += 0x7FFFu + ((u>>16)&1u);
    return (unsigned short)(u>>16);
}
__device__ inline float bf2f(unsigned short h){
    return __uint_as_float(((unsigned)h)<<16);
}
__device__ inline f32x4 mfma16(short8 a, short8 b, f32x4 c){
    return __builtin_amdgcn_mfma_f32_16x16x32_bf16(a, b, c, 0, 0, 0);
}

// ---------------------------------------------------------------------------
// Weight pack: split-bf16 + MFMA B-fragment layout.
// pk[cb][ks][tile][pl][lane][j]; k = ks*32+(lane>>4)*8+j; col = cb*64+tile*16+(lane&15)
// ---------------------------------------------------------------------------
__global__ void pack_kernel(const float* __restrict__ A, const float* __restrict__ B,
                            int Ksplit, int N, int KS, unsigned short* __restrict__ pk, int total)
{
    int t = blockIdx.x*256 + threadIdx.x;
    if (t >= total) return;
    int j = t & 7, l = (t>>3)&63, tile = (t>>9)&3;
    int rest = t >> 11;
    int ks = rest % KS, cb = rest / KS;
    int k   = ks*32 + ((l>>4)*8) + j;
    int col = cb*64 + tile*16 + (l&15);
    float wv = (k < Ksplit) ? A[(size_t)k*N + col] : B[(size_t)(k-Ksplit)*N + col];
    unsigned short hi = f2bf(wv);
    unsigned short lo = f2bf(wv - bf2f(hi));
    size_t base = ((size_t)(cb*KS + ks)*4 + tile)*1024 + (size_t)l*8 + j;
    pk[base]       = hi;   // pl=0
    pk[base + 512] = lo;   // pl=1
}

// ---------------------------------------------------------------------------
// Leaf: h[r][c] = tanh(sum_k shape[k][r]*Wb[k][c] + bb[c]) -> split-bf16 planes
// ---------------------------------------------------------------------------
__global__ __launch_bounds__(256) void leaf_split_kernel(
    const float* __restrict__ shape, const float* __restrict__ Wb,
    const float* __restrict__ bb,
    unsigned short* __restrict__ hhi, unsigned short* __restrict__ hlo)
{
    __shared__ float Xs[16][132];
    const int r0 = blockIdx.x * 16;
    const int t  = threadIdx.x;
    for (int it = 0; it < 2; ++it) {
        int task = t + it * 256;
        int r  = task & 15;
        int kg = task >> 4;
        #pragma unroll
        for (int j = 0; j < 4; ++j)
            Xs[r][4*kg + j] = shape[(size_t)(4*kg + j) * LEAF + r0 + r];
    }
    __syncthreads();
    float acc[16];
    #pragma unroll
    for (int r = 0; r < 16; ++r) acc[r] = 0.f;
    const int c = t;
    for (int k = 0; k < BOX; k += 4) {
        float w0 = Wb[(k+0)*LATENT + c];
        float w1 = Wb[(k+1)*LATENT + c];
        float w2 = Wb[(k+2)*LATENT + c];
        float w3 = Wb[(k+3)*LATENT + c];
        #pragma unroll
        for (int r = 0; r < 16; ++r) {
            float4 x = *reinterpret_cast<const float4*>(&Xs[r][k]);
            acc[r] = fmaf(x.x, w0, acc[r]);
            acc[r] = fmaf(x.y, w1, acc[r]);
            acc[r] = fmaf(x.z, w2, acc[r]);
            acc[r] = fmaf(x.w, w3, acc[r]);
        }
    }
    float bias = bb[c];
    #pragma unroll
    for (int r = 0; r < 16; ++r) {
        float v = tanhf(acc[r] + bias);
        unsigned short hv = f2bf(v);
        size_t o = (size_t)(r0 + r) * LATENT + c;
        hhi[o] = hv;
        hlo[o] = f2bf(v - bf2f(hv));
    }
}

// ---------------------------------------------------------------------------
// K1: stage-1 both paths. cb<8: U cols 64cb.. (K=512 from [a|b]);
//     cb>=8: V cols (K=320: a (256) + param (64)).
// Block: 4 waves x NSUB x 16 rows x 64 cols. B double-buffered in LDS.
// ---------------------------------------------------------------------------
template<int NSUB>
__global__ __launch_bounds__(256) void k1_kernel(
    const unsigned short* __restrict__ hhi, const unsigned short* __restrict__ hlo,
    const float* __restrict__ param,
    const unsigned short* __restrict__ wcatpk, const unsigned short* __restrict__ wscatpk,
    const float* __restrict__ b1, const float* __restrict__ bs1,
    unsigned short* __restrict__ Uhi, unsigned short* __restrict__ Ulo,
    unsigned short* __restrict__ Vhi, unsigned short* __restrict__ Vlo,
    int start, int n)
{
    __shared__ __align__(16) unsigned short ldsB[2*4096];
    const int t = threadIdx.x, lane = t & 63, w = t >> 6;
    const int cb = blockIdx.y;
    const bool isV = cb >= 8;
    const int cbl = isV ? cb - 8 : cb;
    const int KS  = isV ? 10 : 16;
    const unsigned short* pk = (isV ? wscatpk : wcatpk) + (size_t)cbl * KS * 4096;
    const int row0  = blockIdx.x * NSUB * 64;
    const int cbase = 2 * (start - LEAF);

    f32x4 acc[NSUB][4];
    #pragma unroll
    for (int s = 0; s < NSUB; ++s)
        #pragma unroll
        for (int c = 0; c < 4; ++c) acc[s][c] = (f32x4){0.f, 0.f, 0.f, 0.f};

    { // prologue: stage ks=0 into buf0
        short8 v0 = *(const short8*)(pk + (size_t)t*8);
        short8 v1 = *(const short8*)(pk + (size_t)(t+256)*8);
        *(short8*)(ldsB + t*8) = v0;
        *(short8*)(ldsB + (t+256)*8) = v1;
    }
    __syncthreads();

    for (int ks = 0; ks < KS; ++ks) {
        const int cur = ks & 1, nxt = ks + 1;
        const bool hasNext = nxt < KS;
        short8 st0, st1;
        if (hasNext) {
            st0 = *(const short8*)(pk + (size_t)nxt*4096 + (size_t)t*8);
            st1 = *(const short8*)(pk + (size_t)nxt*4096 + (size_t)(t+256)*8);
        }
        short8 Ah[NSUB], Al[NSUB];
        #pragma unroll
        for (int s = 0; s < NSUB; ++s) {
            int m = row0 + (s*4 + w)*16 + (lane & 15);
            if (m >= n) m = n - 1;
            if (!isV || ks < 8) {
                int node = cbase + 2*m + (ks >= 8 ? 1 : 0);
                size_t off = (size_t)node*256 + (size_t)(ks & 7)*32 + ((lane >> 4)*8);
                Ah[s] = *(const short8*)(hhi + off);
                Al[s] = *(const short8*)(hlo + off);
            } else {
                int pnode = cbase + 2*m;
                int kb = (ks - 8)*32 + (lane >> 4)*8;
                const float* pp = param + (size_t)pnode*64 + kb;
                #pragma unroll
                for (int e = 0; e < 8; ++e) {
                    float v = pp[e];
                    unsigned short hv = f2bf(v);
                    Ah[s][e] = (short)hv;
                    Al[s][e] = (short)f2bf(v - bf2f(hv));
                }
            }
        }
        const unsigned short* lb = ldsB + cur*4096;
        #pragma unroll
        for (int tile = 0; tile < 4; ++tile) {
            short8 Bh = *(const short8*)(lb + tile*1024 + lane*8);
            short8 Bl = *(const short8*)(lb + tile*1024 + 512 + lane*8);
            #pragma unroll
            for (int s = 0; s < NSUB; ++s) {
                acc[s][tile] = mfma16(Al[s], Bh, acc[s][tile]);
                acc[s][tile] = mfma16(Ah[s], Bl, acc[s][tile]);
                acc[s][tile] = mfma16(Ah[s], Bh, acc[s][tile]);
            }
        }
        if (hasNext) {
            unsigned short* wb = ldsB + (nxt & 1)*4096;
            *(short8*)(wb + t*8) = st0;
            *(short8*)(wb + (t+256)*8) = st1;
        }
        __syncthreads();
    }

    const float* bias = isV ? bs1 : b1;
    unsigned short* ohi = isV ? Vhi : Uhi;
    unsigned short* olo = isV ? Vlo : Ulo;
    #pragma unroll
    for (int s = 0; s < NSUB; ++s) {
        #pragma unroll
        for (int tile = 0; tile < 4; ++tile) {
            int col = cbl*64 + tile*16 + (lane & 15);
            float bv = bias[col];
            #pragma unroll
            for (int r = 0; r < 4; ++r) {
                int m = row0 + (s*4 + w)*16 + (lane >> 4)*4 + r;
                if (m < n) {
                    float v = tanhf(acc[s][tile][r] + bv);
                    unsigned short hv = f2bf(v);
                    size_t o = (size_t)m*512 + col;
                    ohi[o] = hv;
                    olo[o] = f2bf(v - bf2f(hv));
                }
            }
        }
    }
}

// ---------------------------------------------------------------------------
// K2: stage-2 both paths + select + write h planes.
// cb<4: H1 = tanh(U@W2+b2) (rows k2==0); cb>=4: H2 = tanh(V@Ws2+bs2) (k2==1)
// ---------------------------------------------------------------------------
template<int NSUB>
__global__ __launch_bounds__(256) void k2_kernel(
    const unsigned short* __restrict__ Uhi, const unsigned short* __restrict__ Ulo,
    const unsigned short* __restrict__ Vhi, const unsigned short* __restrict__ Vlo,
    const int* __restrict__ kids,
    const unsigned short* __restrict__ w2pk, const unsigned short* __restrict__ ws2pk,
    const float* __restrict__ b2, const float* __restrict__ bs2,
    unsigned short* __restrict__ hhi, unsigned short* __restrict__ hlo,
    int start, int n)
{
    __shared__ __align__(16) unsigned short ldsB[2*4096];
    const int t = threadIdx.x, lane = t & 63, w = t >> 6;
    const int cb = blockIdx.y;
    const bool isSym = cb >= 4;
    const int cbl = isSym ? cb - 4 : cb;
    const unsigned short* pk  = (isSym ? ws2pk : w2pk) + (size_t)cbl * 16 * 4096;
    const unsigned short* Ahi = isSym ? Vhi : Uhi;
    const unsigned short* Alo = isSym ? Vlo : Ulo;
    const int row0 = blockIdx.x * NSUB * 64;

    f32x4 acc[NSUB][4];
    #pragma unroll
    for (int s = 0; s < NSUB; ++s)
        #pragma unroll
        for (int c = 0; c < 4; ++c) acc[s][c] = (f32x4){0.f, 0.f, 0.f, 0.f};

    {
        short8 v0 = *(const short8*)(pk + (size_t)t*8);
        short8 v1 = *(const short8*)(pk + (size_t)(t+256)*8);
        *(short8*)(ldsB + t*8) = v0;
        *(short8*)(ldsB + (t+256)*8) = v1;
    }
    __syncthreads();

    for (int ks = 0; ks < 16; ++ks) {
        const int cur = ks & 1, nxt = ks + 1;
        const bool hasNext = nxt < 16;
        short8 st0, st1;
        if (hasNext) {
            st0 = *(const short8*)(pk + (size_t)nxt*4096 + (size_t)t*8);
            st1 = *(const short8*)(pk + (size_t)nxt*4096 + (size_t)(t+256)*8);
        }
        short8 Ah[NSUB], Al[NSUB];
        #pragma unroll
        for (int s = 0; s < NSUB; ++s) {
            int m = row0 + (s*4 + w)*16 + (lane & 15);
            if (m >= n) m = n - 1;
            size_t off = (size_t)m*512 + (size_t)ks*32 + ((lane >> 4)*8);
            Ah[s] = *(const short8*)(Ahi + off);
            Al[s] = *(const short8*)(Alo + off);
        }
        const unsigned short* lb = ldsB + cur*4096;
        #pragma unroll
        for (int tile = 0; tile < 4; ++tile) {
            short8 Bh = *(const short8*)(lb + tile*1024 + lane*8);
            short8 Bl = *(const short8*)(lb + tile*1024 + 512 + lane*8);
            #pragma unroll
            for (int s = 0; s < NSUB; ++s) {
                acc[s][tile] = mfma16(Al[s], Bh, acc[s][tile]);
                acc[s][tile] = mfma16(Ah[s], Bl, acc[s][tile]);
                acc[s][tile] = mfma16(Ah[s], Bh, acc[s][tile]);
            }
        }
        if (hasNext) {
            unsigned short* wb = ldsB + (nxt & 1)*4096;
            *(short8*)(wb + t*8) = st0;
            *(short8*)(wb + (t+256)*8) = st1;
        }
        __syncthreads();
    }

    const float* bias = isSym ? bs2 : b2;
    const int want = isSym ? 1 : 0;
    #pragma unroll
    for (int s = 0; s < NSUB; ++s) {
        #pragma unroll
        for (int tile = 0; tile < 4; ++tile) {
            int col = cbl*64 + tile*16 + (lane & 15);
            float bv = bias[col];
            #pragma unroll
            for (int r = 0; r < 4; ++r) {
                int m = row0 + (s*4 + w)*16 + (lane >> 4)*4 + r;
                if (m < n && kids[3*(start + m) + 2] == want) {
                    float v = tanhf(acc[s][tile][r] + bv);
                    unsigned short hv = f2bf(v);
                    size_t o = (size_t)(start + m)*256 + col;
                    hhi[o] = hv;
                    hlo[o] = f2bf(v - bf2f(hv));
                }
            }
        }
    }
}

__global__ void final_kernel(const unsigned short* __restrict__ hhi,
                             const unsigned short* __restrict__ hlo,
                             float* __restrict__ out)
{
    int c = threadIdx.x;
    size_t o = (size_t)(NNODE - 1)*256 + c;
    out[c] = bf2f(hhi[o]) + bf2f(hlo[o]);
}

// ======================= legacy fp32 fallback (round-1) =====================
__global__ __launch_bounds__(256) void leaf_kernel_legacy(
    const float* __restrict__ shape, const float* __restrict__ Wb,
    const float* __restrict__ bb, float* __restrict__ h)
{
    __shared__ float Xs[16][132];
    const int r0 = blockIdx.x * 16;
    const int t  = threadIdx.x;
    for (int it = 0; it < 2; ++it) {
        int task = t + it * 256;
        int r  = task & 15;
        int kg = task >> 4;
        #pragma unroll
        for (int j = 0; j < 4; ++j)
            Xs[r][4*kg + j] = shape[(size_t)(4*kg + j) * LEAF + r0 + r];
    }
    __syncthreads();
    float acc[16];
    #pragma unroll
    for (int r = 0; r < 16; ++r) acc[r] = 0.f;
    const int c = t;
    for (int k = 0; k < BOX; k += 4) {
        float w0 = Wb[(k+0)*LATENT + c];
        float w1 = Wb[(k+1)*LATENT + c];
        float w2 = Wb[(k+2)*LATENT + c];
        float w3 = Wb[(k+3)*LATENT + c];
        #pragma unroll
        for (int r = 0; r < 16; ++r) {
            float4 x = *reinterpret_cast<const float4*>(&Xs[r][k]);
            acc[r] = fmaf(x.x, w0, acc[r]);
            acc[r] = fmaf(x.y, w1, acc[r]);
            acc[r] = fmaf(x.z, w2, acc[r]);
            acc[r] = fmaf(x.w, w3, acc[r]);
        }
    }
    float bias = bb[c];
    #pragma unroll
    for (int r = 0; r < 16; ++r)
        h[(size_t)(r0 + r) * LATENT + c] = tanhf(acc[r] + bias);
}

__global__ __launch_bounds__(256) void level_kernel_legacy(
    float* __restrict__ h, const int* __restrict__ kids, const float* __restrict__ param,
    const float* __restrict__ Wl, const float* __restrict__ Wr, const float* __restrict__ b1,
    const float* __restrict__ W2, const float* __restrict__ b2,
    const float* __restrict__ Wsl, const float* __restrict__ Wsr, const float* __restrict__ bs1,
    const float* __restrict__ Ws2, const float* __restrict__ bs2,
    int start, int n)
{
    __shared__ float Xs[16][512];
    __shared__ float Us[16][512];
    __shared__ float Ss[16][64];
    __shared__ int k0s[16], k2s[16], symlist[16];
    __shared__ int nsym_s;
    const int t  = threadIdx.x;
    const int m0 = blockIdx.x * 16;
    __shared__ int k1s[16];
    if (t < 16) {
        int m  = m0 + t;
        int mm = (m < n) ? m : (n - 1);
        int i  = start + mm;
        k0s[t] = kids[3*i] - 1;
        k1s[t] = kids[3*i + 1] - 1;
        k2s[t] = (m < n) ? kids[3*i + 2] : 0;
    }
    __syncthreads();
    if (t == 0) {
        int c = 0;
        for (int r = 0; r < 16; ++r) {
            int m = m0 + r;
            if (m < n && k2s[r]) symlist[c++] = r;
        }
        nsym_s = c;
    }
    for (int r = 0; r < 16; ++r) {
        Xs[r][t]       = h[(size_t)k0s[r] * LATENT + t];
        Xs[r][t + 256] = h[(size_t)k1s[r] * LATENT + t];
    }
    for (int it = 0; it < 4; ++it) {
        int task = t + it * 256;
        int r = task >> 6;
        int k = task & 63;
        Ss[r][k] = param[(size_t)k0s[r] * SYM + k];
    }
    __syncthreads();
    float acc1[16], acc2[16];
    #pragma unroll
    for (int r = 0; r < 16; ++r) { acc1[r] = 0.f; acc2[r] = 0.f; }
    for (int k = 0; k < 256; k += 4) {
        float wa[4], wb[4];
        #pragma unroll
        for (int kk = 0; kk < 4; ++kk) {
            wa[kk] = Wl[(k+kk)*HIDDEN + t];
            wb[kk] = Wl[(k+kk)*HIDDEN + t + 256];
        }
        #pragma unroll
        for (int r = 0; r < 16; ++r) {
            float4 x = *reinterpret_cast<const float4*>(&Xs[r][k]);
            acc1[r] = fmaf(x.x,wa[0],fmaf(x.y,wa[1],fmaf(x.z,wa[2],fmaf(x.w,wa[3],acc1[r]))));
            acc2[r] = fmaf(x.x,wb[0],fmaf(x.y,wb[1],fmaf(x.z,wb[2],fmaf(x.w,wb[3],acc2[r]))));
        }
    }
    for (int k = 0; k < 256; k += 4) {
        float wa[4], wb[4];
        #pragma unroll
        for (int kk = 0; kk < 4; ++kk) {
            wa[kk] = Wr[(k+kk)*HIDDEN + t];
            wb[kk] = Wr[(k+kk)*HIDDEN + t + 256];
        }
        #pragma unroll
        for (int r = 0; r < 16; ++r) {
            float4 x = *reinterpret_cast<const float4*>(&Xs[r][256 + k]);
            acc1[r] = fmaf(x.x,wa[0],fmaf(x.y,wa[1],fmaf(x.z,wa[2],fmaf(x.w,wa[3],acc1[r]))));
            acc2[r] = fmaf(x.x,wb[0],fmaf(x.y,wb[1],fmaf(x.z,wb[2],fmaf(x.w,wb[3],acc2[r]))));
        }
    }
    {
        float bA = b1[t], bB = b1[t + 256];
        #pragma unroll
        for (int r = 0; r < 16; ++r) {
            Us[r][t]       = tanhf(acc1[r] + bA);
            Us[r][t + 256] = tanhf(acc2[r] + bB);
        }
    }
    __syncthreads();
    float acc[16];
    #pragma unroll
    for (int r = 0; r < 16; ++r) acc[r] = 0.f;
    for (int k = 0; k < 512; k += 4) {
        float wv[4];
        #pragma unroll
        for (int kk = 0; kk < 4; ++kk) wv[kk] = W2[(k+kk)*LATENT + t];
        #pragma unroll
        for (int r = 0; r < 16; ++r) {
            float4 x = *reinterpret_cast<const float4*>(&Us[r][k]);
            acc[r] = fmaf(x.x,wv[0],fmaf(x.y,wv[1],fmaf(x.z,wv[2],fmaf(x.w,wv[3],acc[r]))));
        }
    }
    {
        float bc = b2[t];
        #pragma unroll
        for (int r = 0; r < 16; ++r) {
            int m = m0 + r;
            if (m < n && !k2s[r])
                h[(size_t)(start + m) * LATENT + t] = tanhf(acc[r] + bc);
        }
    }
    __syncthreads();
    const int nsym = nsym_s;
    for (int base = 0; base < nsym; base += 4) {
        int sr[4];
        #pragma unroll
        for (int j = 0; j < 4; ++j) {
            int idx = base + j;
            sr[j] = symlist[idx < nsym ? idx : nsym - 1];
        }
        float v1[4], v2[4];
        #pragma unroll
        for (int j = 0; j < 4; ++j) { v1[j] = 0.f; v2[j] = 0.f; }
        for (int k = 0; k < 256; k += 4) {
            float wa[4], wb[4];
            #pragma unroll
            for (int kk = 0; kk < 4; ++kk) {
                wa[kk] = Wsl[(k+kk)*HIDDEN + t];
                wb[kk] = Wsl[(k+kk)*HIDDEN + t + 256];
            }
            #pragma unroll
            for (int j = 0; j < 4; ++j) {
                float4 x = *reinterpret_cast<const float4*>(&Xs[sr[j]][k]);
                v1[j] = fmaf(x.x,wa[0],fmaf(x.y,wa[1],fmaf(x.z,wa[2],fmaf(x.w,wa[3],v1[j]))));
                v2[j] = fmaf(x.x,wb[0],fmaf(x.y,wb[1],fmaf(x.z,wb[2],fmaf(x.w,wb[3],v2[j]))));
            }
        }
        for (int k = 0; k < 64; k += 4) {
            float wa[4], wb[4];
            #pragma unroll
            for (int kk = 0; kk < 4; ++kk) {
                wa[kk] = Wsr[(k+kk)*HIDDEN + t];
                wb[kk] = Wsr[(k+kk)*HIDDEN + t + 256];
            }
            #pragma unroll
            for (int j = 0; j < 4; ++j) {
                float4 x = *reinterpret_cast<const float4*>(&Ss[sr[j]][k]);
                v1[j] = fmaf(x.x,wa[0],fmaf(x.y,wa[1],fmaf(x.z,wa[2],fmaf(x.w,wa[3],v1[j]))));
                v2[j] = fmaf(x.x,wb[0],fmaf(x.y,wb[1],fmaf(x.z,wb[2],fmaf(x.w,wb[3],v2[j]))));
            }
        }
        float bA = bs1[t], bB = bs1[t + 256];
        #pragma unroll
        for (int j = 0; j < 4; ++j) {
            Us[base + j][t]       = tanhf(v1[j] + bA);
            Us[base + j][t + 256] = tanhf(v2[j] + bB);
        }
    }
    __syncthreads();
    for (int base = 0; base < nsym; base += 4) {
        float a2[4];
        #pragma unroll
        for (int j = 0; j < 4; ++j) a2[j] = 0.f;
        for (int k = 0; k < 512; k += 4) {
            float wv[4];
            #pragma unroll
            for (int kk = 0; kk < 4; ++kk) wv[kk] = Ws2[(k+kk)*LATENT + t];
            #pragma unroll
            for (int j = 0; j < 4; ++j) {
                float4 x = *reinterpret_cast<const float4*>(&Us[base + j][k]);
                a2[j] = fmaf(x.x,wv[0],fmaf(x.y,wv[1],fmaf(x.z,wv[2],fmaf(x.w,wv[3],a2[j]))));
            }
        }
        float bc = bs2[t];
        #pragma unroll
        for (int j = 0; j < 4; ++j) {
            int idx = base + j;
            if (idx < nsym) {
                int r = symlist[idx];
                int m = m0 + r;
                h[(size_t)(start + m) * LATENT + t] = tanhf(a2[j] + bc);
            }
        }
    }
}
// ===========================================================================

extern "C" void kernel_launch(void* const* d_in, const int* in_sizes, int n_in,
                              void* d_out, int out_size, void* d_ws, size_t ws_size,
                              hipStream_t stream) {
    const int*   kids  = (const int*)  d_in[0];
    const float* shape = (const float*)d_in[1];
    const float* param = (const float*)d_in[2];
    const float* Wb    = (const float*)d_in[3];
    const float* bb    = (const float*)d_in[4];
    const float* Wl    = (const float*)d_in[5];
    const float* Wr    = (const float*)d_in[6];
    const float* b1    = (const float*)d_in[7];
    const float* W2    = (const float*)d_in[8];
    const float* b2    = (const float*)d_in[9];
    const float* Wsl   = (const float*)d_in[10];
    const float* Wsr   = (const float*)d_in[11];
    const float* bs1   = (const float*)d_in[12];
    const float* Ws2   = (const float*)d_in[13];
    const float* bs2   = (const float*)d_in[14];
    float* out = (float*)d_out;

    const size_t NEED = 69861376;
    if (ws_size < NEED) {
        // legacy fp32 path
        float* h = (float*)d_ws;
        leaf_kernel_legacy<<<LEAF/16, 256, 0, stream>>>(shape, Wb, bb, h);
        int start = LEAF;
        for (int n = LEAF/2; n >= 1; n >>= 1) {
            int grid = (n + 15) / 16;
            level_kernel_legacy<<<grid, 256, 0, stream>>>(h, kids, param,
                Wl, Wr, b1, W2, b2, Wsl, Wsr, bs1, Ws2, bs2, start, n);
            start += n;
        }
        hipMemcpyAsync(out, h + (size_t)(NNODE - 1) * LATENT,
                       LATENT * sizeof(float), hipMemcpyDeviceToDevice, stream);
        return;
    }

    char* ws = (char*)d_ws;
    unsigned short* hhi    = (unsigned short*)(ws + 0);
    unsigned short* hlo    = (unsigned short*)(ws + 16777216);
    unsigned short* Uhi    = (unsigned short*)(ws + 33554432);
    unsigned short* Ulo    = (unsigned short*)(ws + 41943040);
    unsigned short* Vhi    = (unsigned short*)(ws + 50331648);
    unsigned short* Vlo    = (unsigned short*)(ws + 58720256);
    unsigned short* wcatpk = (unsigned short*)(ws + 67108864);
    unsigned short* wscatpk= (unsigned short*)(ws + 68157440);
    unsigned short* w2pk   = (unsigned short*)(ws + 68812800);
    unsigned short* ws2pk  = (unsigned short*)(ws + 69337088);

    // pack weights (split-bf16, fragment order)
    pack_kernel<<<1024, 256, 0, stream>>>(Wl,  Wr,  256, 512, 16, wcatpk,  262144);
    pack_kernel<<< 640, 256, 0, stream>>>(Wsl, Wsr, 256, 512, 10, wscatpk, 163840);
    pack_kernel<<< 512, 256, 0, stream>>>(W2,  W2,  512, 256, 16, w2pk,    131072);
    pack_kernel<<< 512, 256, 0, stream>>>(Ws2, Ws2, 512, 256, 16, ws2pk,   131072);

    leaf_split_kernel<<<LEAF/16, 256, 0, stream>>>(shape, Wb, bb, hhi, hlo);

    int start = LEAF;
    for (int n = LEAF/2; n >= 1; n >>= 1) {
        int nsub = (n >= 256) ? 4 : ((n >= 128) ? 2 : 1);
        int rt = (n + nsub*64 - 1) / (nsub*64);
        dim3 g1(rt, 16), g2(rt, 8);
        switch (nsub) {
        case 4:
            k1_kernel<4><<<g1, 256, 0, stream>>>(hhi, hlo, param, wcatpk, wscatpk,
                b1, bs1, Uhi, Ulo, Vhi, Vlo, start, n);
            k2_kernel<4><<<g2, 256, 0, stream>>>(Uhi, Ulo, Vhi, Vlo, kids, w2pk, ws2pk,
                b2, bs2, hhi, hlo, start, n);
            break;
        case 2:
            k1_kernel<2><<<g1, 256, 0, stream>>>(hhi, hlo, param, wcatpk, wscatpk,
                b1, bs1, Uhi, Ulo, Vhi, Vlo, start, n);
            k2_kernel<2><<<g2, 256, 0, stream>>>(Uhi, Ulo, Vhi, Vlo, kids, w2pk, ws2pk,
                b2, bs2, hhi, hlo, start, n);
            break;
        default:
            k1_kernel<1><<<g1, 256, 0, stream>>>(hhi, hlo, param, wcatpk, wscatpk,
                b1, bs1, Uhi, Ulo, Vhi, Vlo, start, n);
            k2_kernel<1><<<g2, 256, 0, stream>>>(Uhi, Ulo, Vhi, Vlo, kids, w2pk, ws2pk,
                b2, bs2, hhi, hlo, start, n);
            break;
        }
        start += n;
    }

    final_kernel<<<1, 256, 0, stream>>>(hhi, hlo, out);
}